// Round 14
// baseline (292.655 us; speedup 1.0000x reference)
//
#include <hip/hip_runtime.h>
#include <math.h>

#define Mq 12288          // B*T
#define Nq 768            // C (per-matrix output width)
#define Kq 768            // C (reduce dim)
#define Tq 768
#define Bq 16
#define Cq 768
#define BK 64             // K-tile (bf16) = 128 B = 8 x 16B chunks
#define BM 128            // M-tile (tokens) — proven 128x128 tile

typedef __bf16 bf16x8 __attribute__((ext_vector_type(8)));
typedef __bf16 bf16x4 __attribute__((ext_vector_type(4)));
typedef __bf16 bf16x2 __attribute__((ext_vector_type(2)));
typedef float  floatx4 __attribute__((ext_vector_type(4)));

// async 16B/lane global->LDS (LDS operand is wave-uniform base; HW adds lane*16)
#define GLD_LDS16(g, l) __builtin_amdgcn_global_load_lds(                      \
    (const __attribute__((address_space(1))) unsigned int*)(g),                \
    (__attribute__((address_space(3))) unsigned int*)(l), 16, 0, 0)

// ---------------------------------------------------------------------------
// Weight conversion only (the mix is now fused into gemm_kvr_f's A-staging):
// 2304 blocks x 256 thr, one float4 of f32 weights -> bf16 pool per thread.
// ---------------------------------------------------------------------------
__global__ __launch_bounds__(256)
void prep_w(const float* __restrict__ Wk, const float* __restrict__ Wv,
            const float* __restrict__ Wr, const float* __restrict__ Wo,
            __bf16* __restrict__ wp)
{
    const int i   = blockIdx.x * 256 + threadIdx.x;   // one float4
    const int a   = i / 147456;                       // which matrix
    const int off = (i - a * 147456) * 4;
    const float* s = (a == 0) ? Wk : (a == 1) ? Wv : (a == 2) ? Wr : Wo;
    const float4 v = *(const float4*)(s + off);
    bf16x4 r = { (__bf16)v.x, (__bf16)v.y, (__bf16)v.z, (__bf16)v.w };
    *(bf16x4*)(wp + (size_t)a * 589824 + off) = r;
}

// ---------------------------------------------------------------------------
// FUSED k|v|r GEMM: m97-structure (frozen: R4/R6/R9/R10 all worse) with the
// token-shift mix computed inside A-staging.
//  - A path: reg-staged from f32 x — load x[row], x[row-1] chunks, mix
//    fmaf(m, xc-xp, xp) (bit-identical to prep), cvt bf16, ds_write_b128
//    into the SAME swizzled As layout the MFMA reader expects.
//    Write addr = rowl*128B + (lane&7)*16B -> per-instr linear, 0 conflicts.
//    Boundary rows (global row % 768 == 0) select zero for x[row-1]
//    (conditional load: no OOB access at row 0).
//  - B path: unchanged global_load_lds width-16.
//  - Eliminates: 54 MB xk/xv/xr write (prep) + 54 MB read (gemm1); A-source
//    x is shared across matids -> 3x smaller per-XCD A working set.
// Reader/MFMA/epilogue byte-identical to the R11 champion.
// ---------------------------------------------------------------------------
__global__ __launch_bounds__(256, 3)
void gemm_kvr_f(const float* __restrict__ X,
                const float* __restrict__ mk, const float* __restrict__ mv,
                const float* __restrict__ mr,
                const __bf16* __restrict__ W,
                __bf16* __restrict__ OUTb)
{
    __shared__ __bf16 As[BM * BK];    // 16 KB (tokens, mixed on the fly)
    __shared__ __bf16 Bs[128 * BK];   // 16 KB (channels)

    const int STRIPS = 18;

    // ---- XCD-aware block swizzle (8 XCDs, 96 m-tiles = 8 x 12)
    const int i_    = blockIdx.x;
    const int xcd   = i_ & 7;
    const int j_    = i_ >> 3;
    const int strip = j_ % STRIPS;
    const int mt    = xcd * 12 + j_ / STRIPS;

    const int tid   = threadIdx.x;
    const int wave  = tid >> 6;
    const int lane  = tid & 63;
    const int m0    = mt * BM;
    const int matid = strip / 6;
    const int n0    = (strip % 6) * 128;
    const int wn0   = strip * 128;

    const float* MIX = (matid == 0) ? mk : (matid == 1) ? mv : mr;

    // ---- B staging (unchanged): 1024 B per gld_lds = 8 rows of 128 B
    const int r8 = lane >> 3;             // row within 8-row group
    const int sc = (lane & 7) ^ r8;       // XOR-8 swizzled source chunk
    const __bf16* gB[4];  __bf16* lB[4];
#pragma unroll
    for (int i = 0; i < 4; ++i) {
        const int row = (wave * 4 + i) * 8 + r8;
        gB[i] = W + (size_t)(wn0 + row) * Kq + sc * 8;
        lB[i] = Bs + (wave * 4 + i) * 512;
    }

    // ---- A fused-mix staging coords
    const float* gx[4];  bool zb[4];  __bf16* wA[4];
#pragma unroll
    for (int i = 0; i < 4; ++i) {
        const int rowl = (wave * 4 + i) * 8 + r8;
        const int grow = m0 + rowl;
        gx[i] = X + (size_t)grow * Cq + sc * 8;
        zb[i] = (grow % Tq) == 0;             // t==0: x[prev] is zero
        wA[i] = As + rowl * 64 + (lane & 7) * 8;   // = swizzled chunk slot
    }

    // ---- reader coords: wave (wm,wn) owns tokens [wm*64,+64) x ch [wn*64,+64)
    const int wm   = wave & 1;
    const int wn   = wave >> 1;
    const int xRow = wm * 64 + (lane & 15);
    const int wRow = wn * 64 + (lane & 15);
    const int lk   = lane >> 4;

    floatx4 acc[4][4];
#pragma unroll
    for (int i = 0; i < 4; ++i)
#pragma unroll
        for (int j = 0; j < 4; ++j) acc[i][j] = (floatx4){0.f, 0.f, 0.f, 0.f};

    for (int kt = 0; kt < Kq / BK; ++kt) {
        // B: async global->LDS first (latency hides under the mix work)
#pragma unroll
        for (int i = 0; i < 4; ++i) { GLD_LDS16(gB[i], lB[i]); gB[i] += BK; }

        // A: load f32 x chunks, mix, convert, ds_write (swizzled slot)
        const float4 mA = *(const float4*)(MIX + kt * 64 + sc * 8);
        const float4 mB = *(const float4*)(MIX + kt * 64 + sc * 8 + 4);
#pragma unroll
        for (int i = 0; i < 4; ++i) {
            const float* xc = gx[i] + kt * 64;
            const float4 c0 = *(const float4*)(xc);
            const float4 c1 = *(const float4*)(xc + 4);
            float4 p0 = make_float4(0.f, 0.f, 0.f, 0.f);
            float4 p1 = make_float4(0.f, 0.f, 0.f, 0.f);
            if (!zb[i]) {
                p0 = *(const float4*)(xc - Cq);
                p1 = *(const float4*)(xc - Cq + 4);
            }
            bf16x8 o;
            o[0] = (__bf16)fmaf(mA.x, c0.x - p0.x, p0.x);
            o[1] = (__bf16)fmaf(mA.y, c0.y - p0.y, p0.y);
            o[2] = (__bf16)fmaf(mA.z, c0.z - p0.z, p0.z);
            o[3] = (__bf16)fmaf(mA.w, c0.w - p0.w, p0.w);
            o[4] = (__bf16)fmaf(mB.x, c1.x - p1.x, p1.x);
            o[5] = (__bf16)fmaf(mB.y, c1.y - p1.y, p1.y);
            o[6] = (__bf16)fmaf(mB.z, c1.z - p1.z, p1.z);
            o[7] = (__bf16)fmaf(mB.w, c1.w - p1.w, p1.w);
            *(bf16x8*)wA[i] = o;                 // ds_write_b128, linear
        }
        __syncthreads();                  // drains vmcnt (B) + lgkm (A writes)

#pragma unroll
        for (int kk = 0; kk < 2; ++kk) {
            bf16x8 wF[4], xF[4];
#pragma unroll
            for (int i = 0; i < 4; ++i) {
                const int r = wRow + i * 16;
                wF[i] = *(const bf16x8*)(Bs + r * BK +
                                         (((kk << 2) | lk) ^ (r & 7)) * 8);
            }
#pragma unroll
            for (int j = 0; j < 4; ++j) {
                const int r = xRow + j * 16;
                xF[j] = *(const bf16x8*)(As + r * BK +
                                         (((kk << 2) | lk) ^ (r & 7)) * 8);
            }
#pragma unroll
            for (int i = 0; i < 4; ++i)
#pragma unroll
                for (int j = 0; j < 4; ++j)
                    acc[i][j] = __builtin_amdgcn_mfma_f32_16x16x32_bf16(
                        wF[i], xF[j], acc[i][j], 0, 0, 0);
        }
        __syncthreads();                  // LDS reads done before overwrite
    }

    // ---- epilogue (champion, rcpf-sigmoid R11-proven)
#pragma unroll
    for (int j = 0; j < 4; ++j) {
        const int tok = m0 + wm * 64 + j * 16 + (lane & 15);
#pragma unroll
        for (int i = 0; i < 4; ++i) {
            const int ch = n0 + wn * 64 + i * 16 + (lane >> 4) * 4;
            float v0 = acc[i][j][0], v1 = acc[i][j][1];
            float v2 = acc[i][j][2], v3 = acc[i][j][3];
            if (matid == 0) {
                v0 = expf(fminf(v0, 60.f)); v1 = expf(fminf(v1, 60.f));
                v2 = expf(fminf(v2, 60.f)); v3 = expf(fminf(v3, 60.f));
            } else if (matid == 2) {
                v0 = __builtin_amdgcn_rcpf(1.f + expf(-v0));
                v1 = __builtin_amdgcn_rcpf(1.f + expf(-v1));
                v2 = __builtin_amdgcn_rcpf(1.f + expf(-v2));
                v3 = __builtin_amdgcn_rcpf(1.f + expf(-v3));
            }
            bf16x4 o = { (__bf16)v0, (__bf16)v1, (__bf16)v2, (__bf16)v3 };
            *(bf16x4*)(OUTb + (size_t)matid * Mq * Nq +
                       (size_t)tok * Nq + ch) = o;
        }
    }
}

// ---------------------------------------------------------------------------
// Final Wo GEMM: m97-structure, champion-exact (f32 output).
// ---------------------------------------------------------------------------
__global__ __launch_bounds__(256, 3)
void gemm_o(const __bf16* __restrict__ A0, const __bf16* __restrict__ W,
            float* __restrict__ OUTf)
{
    __shared__ __bf16 As[BM * BK];
    __shared__ __bf16 Bs[128 * BK];

    const int STRIPS = 6;
    const int i_    = blockIdx.x;
    const int xcd   = i_ & 7;
    const int j_    = i_ >> 3;
    const int strip = j_ % STRIPS;
    const int mt    = xcd * 12 + j_ / STRIPS;

    const int tid   = threadIdx.x;
    const int wave  = tid >> 6;
    const int lane  = tid & 63;
    const int m0    = mt * BM;
    const int n0    = strip * 128;

    const int r8 = lane >> 3;
    const int sc = (lane & 7) ^ r8;
    const __bf16* gA[4];  __bf16* lA[4];
    const __bf16* gB[4];  __bf16* lB[4];
#pragma unroll
    for (int i = 0; i < 4; ++i) {
        const int row = (wave * 4 + i) * 8 + r8;
        gA[i] = A0 + (size_t)(m0 + row) * Kq + sc * 8;
        lA[i] = As + (wave * 4 + i) * 512;
        gB[i] = W + (size_t)(n0 + row) * Kq + sc * 8;
        lB[i] = Bs + (wave * 4 + i) * 512;
    }

    const int wm   = wave & 1;
    const int wn   = wave >> 1;
    const int xRow = wm * 64 + (lane & 15);
    const int wRow = wn * 64 + (lane & 15);
    const int lk   = lane >> 4;

    floatx4 acc[4][4];
#pragma unroll
    for (int i = 0; i < 4; ++i)
#pragma unroll
        for (int j = 0; j < 4; ++j) acc[i][j] = (floatx4){0.f, 0.f, 0.f, 0.f};

    for (int kt = 0; kt < Kq / BK; ++kt) {
#pragma unroll
        for (int i = 0; i < 4; ++i) { GLD_LDS16(gA[i], lA[i]); gA[i] += BK; }
#pragma unroll
        for (int i = 0; i < 4; ++i) { GLD_LDS16(gB[i], lB[i]); gB[i] += BK; }
        __syncthreads();

#pragma unroll
        for (int kk = 0; kk < 2; ++kk) {
            bf16x8 wF[4], xF[4];
#pragma unroll
            for (int i = 0; i < 4; ++i) {
                const int r = wRow + i * 16;
                wF[i] = *(const bf16x8*)(Bs + r * BK +
                                         (((kk << 2) | lk) ^ (r & 7)) * 8);
            }
#pragma unroll
            for (int j = 0; j < 4; ++j) {
                const int r = xRow + j * 16;
                xF[j] = *(const bf16x8*)(As + r * BK +
                                         (((kk << 2) | lk) ^ (r & 7)) * 8);
            }
#pragma unroll
            for (int i = 0; i < 4; ++i)
#pragma unroll
                for (int j = 0; j < 4; ++j)
                    acc[i][j] = __builtin_amdgcn_mfma_f32_16x16x32_bf16(
                        wF[i], xF[j], acc[i][j], 0, 0, 0);
        }
        __syncthreads();
    }

#pragma unroll
    for (int j = 0; j < 4; ++j) {
        const int tok = m0 + wm * 64 + j * 16 + (lane & 15);
#pragma unroll
        for (int i = 0; i < 4; ++i) {
            const int ch = n0 + wn * 64 + i * 16 + (lane >> 4) * 4;
            floatx4 o = acc[i][j];
            *(floatx4*)(OUTf + (size_t)tok * Nq + ch) = o;
        }
    }
}

// ---------------------------------------------------------------------------
// Segmented RWKV scan (champion geometry — best of all 4 measured cells):
// block (64,16), grid (6,16), bf16x2 + rcp (R5: -9.5 us).
// ---------------------------------------------------------------------------
#define SEG 16
#define SLEN (Tq / SEG)   // 48

__global__ __launch_bounds__(1024)
void scan_kernel(const __bf16* __restrict__ kb, const __bf16* __restrict__ vb,
                 __bf16* rb,
                 const float* __restrict__ td, const float* __restrict__ tf)
{
    __shared__ float2 aS[SEG][64];
    __shared__ float2 bS[SEG][64];

    const int cx  = threadIdx.x;          // 0..63 -> channel pair
    const int seg = threadIdx.y;          // 0..15
    const int c0  = blockIdx.x * 128 + cx * 2;
    const int b   = blockIdx.y;

    const float d0 = expf(td[c0]),     d1 = expf(td[c0 + 1]);
    const float w0 = expf(-d0),        w1 = expf(-d1);      // per-step decay
    const float u0 = expf(tf[c0]),     u1 = expf(tf[c0 + 1]);

    const size_t base = ((size_t)b * Tq + seg * SLEN) * Cq + c0;

    // phase 1: local segment sums (zero init)
    float a0 = 0.f, a1 = 0.f, s0 = 0.f, s1 = 0.f;
#pragma unroll 4
    for (int t = 0; t < SLEN; ++t) {
        const size_t idx = base + (size_t)t * Cq;
        const bf16x2 k2 = *(const bf16x2*)(kb + idx);
        const bf16x2 v2 = *(const bf16x2*)(vb + idx);
        const float k0 = (float)k2[0], k1 = (float)k2[1];
        a0 = fmaf(w0, a0, k0 * (float)v2[0]);
        a1 = fmaf(w1, a1, k1 * (float)v2[1]);
        s0 = fmaf(w0, s0, k0);
        s1 = fmaf(w1, s1, k1);
    }
    aS[seg][cx] = make_float2(a0, a1);
    bS[seg][cx] = make_float2(s0, s1);
    __syncthreads();

    // phase 2: serial prefix over segments (first row of threads)
    if (seg == 0) {
        const float W0 = expf(-d0 * (float)SLEN);   // w0^SLEN
        const float W1 = expf(-d1 * (float)SLEN);
        float ia0 = 0.f, ia1 = 0.f, ib0 = 0.f, ib1 = 0.f;
#pragma unroll
        for (int s = 0; s < SEG; ++s) {
            const float2 ta = aS[s][cx];
            const float2 tb = bS[s][cx];
            aS[s][cx] = make_float2(ia0, ia1);
            bS[s][cx] = make_float2(ib0, ib1);
            ia0 = fmaf(W0, ia0, ta.x);  ia1 = fmaf(W1, ia1, ta.y);
            ib0 = fmaf(W0, ib0, tb.x);  ib1 = fmaf(W1, ib1, tb.y);
        }
    }
    __syncthreads();

    // phase 3: outputs with incoming state
    const float2 ain = aS[seg][cx];
    const float2 bin = bS[seg][cx];
    a0 = ain.x; a1 = ain.y; s0 = bin.x; s1 = bin.y;
#pragma unroll 2
    for (int t = 0; t < SLEN; ++t) {
        const size_t idx = base + (size_t)t * Cq;
        const bf16x2 k2 = *(const bf16x2*)(kb + idx);
        const bf16x2 v2 = *(const bf16x2*)(vb + idx);
        const bf16x2 r2 = *(const bf16x2*)(rb + idx);   // sigmoid(r)
        const float k0 = (float)k2[0], k1 = (float)k2[1];
        const float kv0 = k0 * (float)v2[0], kv1 = k1 * (float)v2[1];
        const float n0 = fmaf(u0, kv0, a0), n1 = fmaf(u1, kv1, a1);
        const float e0 = fmaf(u0, k0, s0) + 1e-8f;
        const float e1 = fmaf(u1, k1, s1) + 1e-8f;
        const float i0 = __builtin_amdgcn_rcpf(e0);
        const float i1 = __builtin_amdgcn_rcpf(e1);
        bf16x2 o = { (__bf16)((float)r2[0] * n0 * i0),
                     (__bf16)((float)r2[1] * n1 * i1) };
        *(bf16x2*)(rb + idx) = o;
        a0 = fmaf(w0, a0, kv0);  a1 = fmaf(w1, a1, kv1);
        s0 = fmaf(w0, s0, k0);   s1 = fmaf(w1, s1, k1);
    }
}

extern "C" void kernel_launch(void* const* d_in, const int* in_sizes, int n_in,
                              void* d_out, int out_size, void* d_ws, size_t ws_size,
                              hipStream_t stream)
{
    const float* x  = (const float*)d_in[0];
    const float* td = (const float*)d_in[1];
    const float* tf = (const float*)d_in[2];
    const float* mk = (const float*)d_in[3];
    const float* mv = (const float*)d_in[4];
    const float* mr = (const float*)d_in[5];
    const float* Wk = (const float*)d_in[6];
    const float* Wv = (const float*)d_in[7];
    const float* Wr = (const float*)d_in[8];
    const float* Wo = (const float*)d_in[9];

    const size_t MC = (size_t)Mq * Cq;      // 9,437,184 elems

    // ws: kbuf | vbuf | rbuf(->rwkv) | weights(bf16 x4)  = ~58 MB
    __bf16* kbuf = (__bf16*)d_ws;
    __bf16* vbuf = kbuf + MC;
    __bf16* rbuf = vbuf + MC;
    __bf16* Wp   = rbuf + MC;
    __bf16* Wob  = Wp + 3 * 589824;

    prep_w<<<2304, 256, 0, stream>>>(Wk, Wv, Wr, Wo, Wp);

    // fused mix + k|v|r GEMM: 18 strips x 96 m-tiles, ONE dispatch
    gemm_kvr_f<<<18 * 96, 256, 0, stream>>>(x, mk, mv, mr, Wp, kbuf);

    scan_kernel<<<dim3(Cq / 128, Bq), dim3(64, SEG), 0, stream>>>(
        kbuf, vbuf, rbuf, td, tf);

    gemm_o<<<6 * 96, 256, 0, stream>>>(rbuf, Wob, (float*)d_out);
}